// Round 5
// baseline (577.794 us; speedup 1.0000x reference)
//
#include <hip/hip_runtime.h>
#include <hip/hip_bf16.h>
#include <stdint.h>

#define IN_F 4096
#define OUT_F 4096
#define NTOK 8192

typedef __attribute__((ext_vector_type(8))) __bf16 bf16x8;
typedef __attribute__((ext_vector_type(4))) float f32x4;

__device__ __forceinline__ unsigned short f2bf(float f) {
    unsigned u = __float_as_uint(f);
    u += 0x7fffu + ((u >> 16) & 1u);   // RNE
    return (unsigned short)(u >> 16);
}

// --- zero the f32 W accumulator (own kernel, not SDMA memset) ---
__global__ void zero_kernel(float4* __restrict__ p, int n4) {
    int stride = gridDim.x * blockDim.x;
    float4 z = {0.f, 0.f, 0.f, 0.f};
    for (int i = blockIdx.x * blockDim.x + threadIdx.x; i < n4; i += stride) p[i] = z;
}

// --- fused: COO scatter-add into f32 W  ||  x f32->bf16 (independent ops) ---
#define SCAT_BLOCKS 2048
__global__ void scatter_cvtx_kernel(const float* __restrict__ vals,
                                    const int* __restrict__ rows,
                                    const int* __restrict__ cols,
                                    float* __restrict__ W, int nnz,
                                    const float4* __restrict__ x4,
                                    ushort4* __restrict__ xb4, int nx4) {
    if (blockIdx.x < SCAT_BLOCKS) {
        int stride = SCAT_BLOCKS * 256;
        for (int i = blockIdx.x * 256 + threadIdx.x; i < nnz; i += stride)
            atomicAdd(&W[(size_t)rows[i] * IN_F + cols[i]], vals[i]);
    } else {
        int stride = (gridDim.x - SCAT_BLOCKS) * 256;
        for (int i = (blockIdx.x - SCAT_BLOCKS) * 256 + threadIdx.x; i < nx4; i += stride) {
            float4 v = x4[i];
            ushort4 o;
            o.x = f2bf(v.x); o.y = f2bf(v.y); o.z = f2bf(v.z); o.w = f2bf(v.w);
            xb4[i] = o;
        }
    }
}

// --- W f32 -> bf16 (must follow scatter) ---
__global__ void cvtw_kernel(const float4* __restrict__ in, ushort4* __restrict__ out, int n4) {
    int stride = gridDim.x * blockDim.x;
    for (int i = blockIdx.x * blockDim.x + threadIdx.x; i < n4; i += stride) {
        float4 v = in[i];
        ushort4 o;
        o.x = f2bf(v.x); o.y = f2bf(v.y); o.z = f2bf(v.z); o.w = f2bf(v.w);
        out[i] = o;
    }
}

// ---------------------------------------------------------------------------
// NT GEMM: C = A * B^T + bias. 256x256 tile, 8 waves, BK=32, 4-deep pipeline
// with counted vmcnt(8); 4 phases per K-tile, each {ds_read frag-pair,
// 1 prefetch gload_lds, s_barrier, setprio(1), 8 MFMA, setprio(0), s_barrier}.
// All barriers are asm-with-memory-clobber (loads can't hoist across); the
// tile-top vmcnt+barrier (correctness) is unchanged from the proven R3 kernel.
// ---------------------------------------------------------------------------
#define GLD_LDS16(gp, lp)                                              \
    __builtin_amdgcn_global_load_lds(                                  \
        (__attribute__((address_space(1))) void*)(void*)(gp),          \
        (__attribute__((address_space(3))) void*)(lp), 16, 0, 0)

#define STAGE(tt) do {                                                 \
    const int _b = ((tt) & 3) * 16384;                                 \
    const size_t _k = (size_t)(tt) * 32;                               \
    GLD_LDS16(A0 + _k, &lds[_b + ldst0]);                              \
    GLD_LDS16(A1 + _k, &lds[_b + ldst1]);                              \
    GLD_LDS16(B0 + _k, &lds[_b + 8192 + ldst0]);                       \
    GLD_LDS16(B1 + _k, &lds[_b + 8192 + ldst1]);                       \
} while (0)

#define PBAR() asm volatile("s_barrier" ::: "memory")

#define MFMA_PAIR(m0_)                                                         \
    do {                                                                       \
        __builtin_amdgcn_s_setprio(1);                                         \
        _Pragma("unroll")                                                      \
        for (int n = 0; n < 4; ++n)                                            \
            acc[m0_][n] = __builtin_amdgcn_mfma_f32_16x16x32_bf16(af[m0_], bg[n], acc[m0_][n], 0, 0, 0); \
        _Pragma("unroll")                                                      \
        for (int n = 0; n < 4; ++n)                                            \
            acc[m0_ + 1][n] = __builtin_amdgcn_mfma_f32_16x16x32_bf16(af[m0_ + 1], bg[n], acc[m0_ + 1][n], 0, 0, 0); \
        __builtin_amdgcn_s_setprio(0);                                         \
    } while (0)

template<int VM>
__device__ __forceinline__ void kiter(int t,
        const ushort* __restrict__ A0, const ushort* __restrict__ A1,
        const ushort* __restrict__ B0, const ushort* __restrict__ B1,
        ushort* lds, int ldst0, int ldst1,
        const int (&aoff)[8], const int (&boff)[4], f32x4 (&acc)[8][4]) {
    // tile-top: correctness-critical counted wait + barrier (proven in R3)
    if constexpr (VM == 8)      asm volatile("s_waitcnt vmcnt(8)\n\ts_barrier" ::: "memory");
    else if constexpr (VM == 4) asm volatile("s_waitcnt vmcnt(4)\n\ts_barrier" ::: "memory");
    else                        asm volatile("s_waitcnt vmcnt(0)\n\ts_barrier" ::: "memory");

    const int bb = (t & 3) * 16384;
    const int sb = ((t + 3) & 3) * 16384;
    const size_t sk = (size_t)(t + 3) * 32;
    const bool pf = (t + 3) < (IN_F / 32);
    bf16x8 af[8], bg[4];

    // ---- phase 0: B frags + A pair 0, stage A-half0, MFMA m0,m1 ----
    bg[0] = *(const bf16x8*)&lds[bb + 8192 + boff[0]];
    bg[1] = *(const bf16x8*)&lds[bb + 8192 + boff[1]];
    bg[2] = *(const bf16x8*)&lds[bb + 8192 + boff[2]];
    bg[3] = *(const bf16x8*)&lds[bb + 8192 + boff[3]];
    af[0] = *(const bf16x8*)&lds[bb + aoff[0]];
    af[1] = *(const bf16x8*)&lds[bb + aoff[1]];
    if (pf) GLD_LDS16(A0 + sk, &lds[sb + ldst0]);
    PBAR();
    MFMA_PAIR(0);
    PBAR();
    // ---- phase 1: A pair 1, stage A-half1, MFMA m2,m3 ----
    af[2] = *(const bf16x8*)&lds[bb + aoff[2]];
    af[3] = *(const bf16x8*)&lds[bb + aoff[3]];
    if (pf) GLD_LDS16(A1 + sk, &lds[sb + ldst1]);
    PBAR();
    MFMA_PAIR(2);
    PBAR();
    // ---- phase 2: A pair 2, stage B-half0, MFMA m4,m5 ----
    af[4] = *(const bf16x8*)&lds[bb + aoff[4]];
    af[5] = *(const bf16x8*)&lds[bb + aoff[5]];
    if (pf) GLD_LDS16(B0 + sk, &lds[sb + 8192 + ldst0]);
    PBAR();
    MFMA_PAIR(4);
    PBAR();
    // ---- phase 3: A pair 3, stage B-half1, MFMA m6,m7 (tile-top bar follows) ----
    af[6] = *(const bf16x8*)&lds[bb + aoff[6]];
    af[7] = *(const bf16x8*)&lds[bb + aoff[7]];
    if (pf) GLD_LDS16(B1 + sk, &lds[sb + 8192 + ldst1]);
    PBAR();
    MFMA_PAIR(6);
}

__global__ __launch_bounds__(512, 2)
void gemm_bt_bias(const ushort* __restrict__ A,   // x  bf16 [M][K]
                  const ushort* __restrict__ B,   // W  bf16 [N][K]
                  const float* __restrict__ bias,
                  float* __restrict__ C) {        // [M][N] f32
    constexpr int N = OUT_F, K = IN_F;
    constexpr int NT = K / 32;                    // 128 K-tiles

    extern __shared__ ushort lds[];               // 128 KB: 4 bufs x (A 8K + B 8K elems)

    const int tid  = threadIdx.x;
    const int lane = tid & 63;
    const int wid  = tid >> 6;

    // XCD-contiguous block swizzle (512 blocks, 8 XCDs, 64 per XCD)
    const int bid = blockIdx.x;
    const int nb  = (bid & 7) * 64 + (bid >> 3);
    const int by = nb >> 4, bx = nb & 15;         // 32 M-tiles x 16 N-tiles
    const int brow = by * 256, bcol = bx * 256;

    const int wr = wid >> 2, wc = wid & 3;        // wave -> 128x64 output

    // staging: linear LDS dest elem d -> global element swz(d)
    const int d0 = tid * 8, d1 = (512 + tid) * 8;
    const int s0 = d0 ^ (((d0 >> 6) & 7) << 3);
    const int s1 = d1 ^ (((d1 >> 6) & 7) << 3);
    const ushort* A0 = A + (size_t)(brow + (s0 >> 5)) * K + (s0 & 31);
    const ushort* A1 = A + (size_t)(brow + (s1 >> 5)) * K + (s1 & 31);
    const ushort* B0 = B + (size_t)(bcol + (s0 >> 5)) * K + (s0 & 31);
    const ushort* B1 = B + (size_t)(bcol + (s1 >> 5)) * K + (s1 & 31);
    const int ldst0 = (wid * 64) * 8;             // wave-uniform LDS bases (+lane*16B by HW)
    const int ldst1 = (512 + wid * 64) * 8;

    // swizzled fragment offsets
    const int fr = lane & 15, kq = (lane >> 4) * 8;
    int aoff[8], boff[4];
#pragma unroll
    for (int m = 0; m < 8; ++m) {
        int lin = (wr * 128 + m * 16 + fr) * 32 + kq;
        aoff[m] = lin ^ (((lin >> 6) & 7) << 3);
    }
#pragma unroll
    for (int n = 0; n < 4; ++n) {
        int lin = (wc * 64 + n * 16 + fr) * 32 + kq;
        boff[n] = lin ^ (((lin >> 6) & 7) << 3);
    }

    f32x4 acc[8][4] = {};

    STAGE(0); STAGE(1); STAGE(2);                 // fill pipeline (12 loads in flight)

    for (int t = 0; t < NT - 2; ++t)
        kiter<8>(t, A0, A1, B0, B1, lds, ldst0, ldst1, aoff, boff, acc);
    kiter<4>(NT - 2, A0, A1, B0, B1, lds, ldst0, ldst1, aoff, boff, acc);
    kiter<0>(NT - 1, A0, A1, B0, B1, lds, ldst0, ldst1, aoff, boff, acc);

    // epilogue: C/D layout col=lane&15, row=(lane>>4)*4+j  [m89]
    const int crow0 = brow + wr * 128;
    const int ccol0 = bcol + wc * 64;
#pragma unroll
    for (int n = 0; n < 4; ++n) {
        const int col = ccol0 + n * 16 + fr;
        const float bv = bias[col];
#pragma unroll
        for (int m = 0; m < 8; ++m) {
            const int r0 = crow0 + m * 16 + (lane >> 4) * 4;
#pragma unroll
            for (int j = 0; j < 4; ++j)
                C[(size_t)(r0 + j) * N + col] = acc[m][n][j] + bv;
        }
    }
}

extern "C" void kernel_launch(void* const* d_in, const int* in_sizes, int n_in,
                              void* d_out, int out_size, void* d_ws, size_t ws_size,
                              hipStream_t stream) {
    const float* x    = (const float*)d_in[0];
    const float* vals = (const float*)d_in[1];
    const int*   rows = (const int*)d_in[2];
    const int*   cols = (const int*)d_in[3];
    const float* bias = (const float*)d_in[4];
    float* out = (float*)d_out;
    const int nnz = in_sizes[1];

    char* ws = (char*)d_ws;
    float*  Wf = (float*)ws;                                  // 64 MB f32 W
    ushort* Wb = (ushort*)(ws + (size_t)64 * 1024 * 1024);    // 32 MB bf16 W
    ushort* Xb = (ushort*)(ws + (size_t)96 * 1024 * 1024);    // 64 MB bf16 x

    zero_kernel<<<2048, 256, 0, stream>>>((float4*)Wf, OUT_F * IN_F / 4);
    scatter_cvtx_kernel<<<4096, 256, 0, stream>>>(vals, rows, cols, Wf, nnz,
                                                  (const float4*)x, (ushort4*)Xb,
                                                  NTOK * IN_F / 4);
    cvtw_kernel<<<2048, 256, 0, stream>>>((const float4*)Wf, (ushort4*)Wb, OUT_F * IN_F / 4);
    gemm_bt_bias<<<dim3((NTOK / 256) * (OUT_F / 256)), 512, 131072, stream>>>(Xb, Wb, bias, out);
}